// Round 3
// 2077.567 us; speedup vs baseline: 1.1269x; 1.1269x over previous
//
#include <hip/hip_runtime.h>
#include <math.h>

typedef unsigned short u16;
typedef __bf16 bf16x8 __attribute__((ext_vector_type(8)));
typedef float floatx4 __attribute__((ext_vector_type(4)));

__device__ __forceinline__ u16 f2bf(float f) {
    unsigned int u = __float_as_uint(f);
    u += 0x7FFFu + ((u >> 16) & 1u);          // round-to-nearest-even
    return (u16)(u >> 16);
}

__device__ __forceinline__ void async_load16(const void* g, void* l) {
    __builtin_amdgcn_global_load_lds(
        (const __attribute__((address_space(1))) unsigned int*)g,
        (__attribute__((address_space(3))) unsigned int*)l, 16, 0, 0);
}

#define BM 128
#define BN 128
#define BK 32

// C[M,N] = A[M,K] @ B[N,K]^T, A/B bf16 (u16 bits), fp32 accumulate.
// Sync structure identical to the verified baseline (__syncthreads only; no
// inline asm), plus: (1) conflict-free LDS swizzle key (row>>1)&3 — every
// 8-lane group of a ds_read_b128 covers all 8 (row-parity, chunk) bank groups;
// (2) double-buffered LDS with next-tile staging issued BEFORE compute so the
// end-of-iter __syncthreads drain overlaps with MFMA (2-phase pipeline);
// (3) XCD-aware chunked block swizzle for A-panel L2 residency.
// OUT_BF16: store C as bf16 bits, else fp32.
// EPI: C = (E - acc)^2  (E fp32 read at same coords)
// blockIdx.z batches via element strides sA/sB/sC/sE (0 -> shared operand).
template<int OUT_BF16, int EPI>
__global__ __launch_bounds__(256)
void gemm_mfma(const u16* __restrict__ A, const u16* __restrict__ B,
               void* __restrict__ Cv, const float* __restrict__ E,
               int N, int K,
               long long sA, long long sB, long long sC, long long sE)
{
    __shared__ u16 As[2][BM * BK];   // 2 x 8 KB, [buf][row][k], chunks XOR-swizzled
    __shared__ u16 Bs[2][BN * BK];   // 2 x 8 KB

    const long long z = blockIdx.z;
    A += z * sA;
    B += z * sB;

    // ---- XCD-aware chunked block swizzle (x-y plane; all our grids have
    //      nwg % 8 == 0, guarded anyway) ----
    const int gx = gridDim.x;
    const int nwg = gx * gridDim.y;
    int wg = blockIdx.y * gx + blockIdx.x;
    if ((nwg & 7) == 0) wg = (wg & 7) * (nwg >> 3) + (wg >> 3);
    const int bx = wg % gx, by = wg / gx;

    const int tid  = threadIdx.x;
    const int w    = tid >> 6;
    const int lane = tid & 63;

    // ---- staging addresses (global_load_lds: LDS dest is lane-ordered) ----
    // LDS row r slot s holds global k-chunk s ^ ((r>>1)&3); dest is linear so
    // the XOR is applied to the per-lane GLOBAL source (m173 pattern).
    // Here (srow>>1)&3 == (lane>>3)&3.
    const int srow = w * 16 + (lane >> 2);
    const int skp  = ((lane & 3) ^ ((lane >> 3) & 3)) * 8;   // swizzled src chunk
    const u16* Ag = A + ((long long)by * BM + srow) * K + skp;
    const u16* Bg = B + ((long long)bx * BN + srow) * K + skp;
    const long long rstep = (long long)64 * K;
    const int lds_off = w * 512 + lane * 8;   // == srow*BK + (lane&3)*8

    // ---- compute-side fragment addressing ----
    const int wm   = (w >> 1) * 64, wn = (w & 1) * 64;   // wave 2x2 in 128x128
    const int frow = lane & 15, quad = lane >> 4;
    const int rsw  = (frow >> 1) & 3;                    // row's swizzle key
    const int slot = (quad ^ rsw) * 8;                   // u16 offset within row

    floatx4 acc[4][4];
#pragma unroll
    for (int i = 0; i < 4; i++)
#pragma unroll
        for (int j = 0; j < 4; j++) acc[i][j] = (floatx4)0.0f;

    const int NT = K / BK;

    // ---- prologue: stage tile 0 into buffer 0 ----
    async_load16(Ag,         &As[0][lds_off]);
    async_load16(Ag + rstep, &As[0][lds_off + 64 * BK]);
    async_load16(Bg,         &Bs[0][lds_off]);
    async_load16(Bg + rstep, &Bs[0][lds_off + 64 * BK]);
    __syncthreads();                         // drains vmcnt -> tile 0 visible

    for (int t = 0; t < NT; ++t) {
        const int cur = t & 1;
        // issue next tile's loads FIRST (async; drained by end-of-iter barrier,
        // so their latency hides under this tile's ds_reads + MFMAs)
        if (t + 1 < NT) {
            const long long ko = (long long)(t + 1) * BK;
            async_load16(Ag + ko,         &As[cur ^ 1][lds_off]);
            async_load16(Ag + ko + rstep, &As[cur ^ 1][lds_off + 64 * BK]);
            async_load16(Bg + ko,         &Bs[cur ^ 1][lds_off]);
            async_load16(Bg + ko + rstep, &Bs[cur ^ 1][lds_off + 64 * BK]);
        }

        union { int4 i4; bf16x8 v; } a[4], b[4];
#pragma unroll
        for (int i = 0; i < 4; i++)
            a[i].i4 = *(const int4*)&As[cur][(wm + 16 * i + frow) * BK + slot];
#pragma unroll
        for (int j = 0; j < 4; j++)
            b[j].i4 = *(const int4*)&Bs[cur][(wn + 16 * j + frow) * BK + slot];
#pragma unroll
        for (int i = 0; i < 4; i++)
#pragma unroll
            for (int j = 0; j < 4; j++)
                acc[i][j] = __builtin_amdgcn_mfma_f32_16x16x32_bf16(
                    a[i].v, b[j].v, acc[i][j], 0, 0, 0);

        __syncthreads();   // all waves' reads of buf[cur] done; buf[cur^1] landed
    }

    // ---- epilogue: C/D layout col=lane&15, row=quad*4+reg ----
    const long long crow0 = (long long)by * BM + wm + quad * 4;
    const long long ccol0 = (long long)bx * BN + wn + frow;
    u16*   Cb = (u16*)Cv   + z * sC;
    float* Cf = (float*)Cv + z * sC;
    const float* Ep = EPI ? (E + z * sE) : nullptr;
#pragma unroll
    for (int i = 0; i < 4; i++) {
#pragma unroll
        for (int r = 0; r < 4; r++) {
            const long long gr = crow0 + 16 * i + r;
#pragma unroll
            for (int j = 0; j < 4; j++) {
                const long long gc = ccol0 + 16 * j;
                float v = acc[i][j][r];
                if (EPI) {
                    const float e = Ep[gr * (long long)N + gc];
                    const float d = e - v;
                    v = d * d;
                }
                if (OUT_BF16) Cb[gr * (long long)N + gc] = f2bf(v);
                else          Cf[gr * (long long)N + gc] = v;
            }
        }
    }
}

// row softmax over 2048 cols: O = bf16(softmax(P * scale)), P fp32
__global__ __launch_bounds__(256)
void softmax_bf16(const float* __restrict__ P, u16* __restrict__ O, float scale)
{
    const long long rb = (long long)blockIdx.x * 2048;
    const float* p = P + rb;
    const int tid = threadIdx.x;

    const float4 x0 = *(const float4*)(p + tid * 8);
    const float4 x1 = *(const float4*)(p + tid * 8 + 4);
    float v[8] = {x0.x, x0.y, x0.z, x0.w, x1.x, x1.y, x1.z, x1.w};

    float m = -1e30f;
#pragma unroll
    for (int j = 0; j < 8; j++) { v[j] *= scale; m = fmaxf(m, v[j]); }
#pragma unroll
    for (int off = 32; off; off >>= 1) m = fmaxf(m, __shfl_xor(m, off));

    __shared__ float smax[4];
    __shared__ float ssum[4];
    const int wid = tid >> 6, lane = tid & 63;
    if (lane == 0) smax[wid] = m;
    __syncthreads();
    m = fmaxf(fmaxf(smax[0], smax[1]), fmaxf(smax[2], smax[3]));

    float s = 0.f;
#pragma unroll
    for (int j = 0; j < 8; j++) { v[j] = __expf(v[j] - m); s += v[j]; }
#pragma unroll
    for (int off = 32; off; off >>= 1) s += __shfl_xor(s, off);
    if (lane == 0) ssum[wid] = s;
    __syncthreads();
    const float inv = 1.f / (ssum[0] + ssum[1] + ssum[2] + ssum[3]);

    unsigned int p0 = f2bf(v[0] * inv) | ((unsigned int)f2bf(v[1] * inv) << 16);
    unsigned int p1 = f2bf(v[2] * inv) | ((unsigned int)f2bf(v[3] * inv) << 16);
    unsigned int p2 = f2bf(v[4] * inv) | ((unsigned int)f2bf(v[5] * inv) << 16);
    unsigned int p3 = f2bf(v[6] * inv) | ((unsigned int)f2bf(v[7] * inv) << 16);
    *(uint4*)(O + rb + tid * 8) = make_uint4(p0, p1, p2, p3);
}

// fp32 -> bf16 bits, 8 elems/thread; n must be a multiple of 2048
__global__ __launch_bounds__(256)
void cast_bf16(const float* __restrict__ S, u16* __restrict__ D)
{
    const long long i = ((long long)blockIdx.x * 256 + threadIdx.x) * 8;
    const float4 a = *(const float4*)(S + i);
    const float4 b = *(const float4*)(S + i + 4);
    unsigned int p0 = f2bf(a.x) | ((unsigned int)f2bf(a.y) << 16);
    unsigned int p1 = f2bf(a.z) | ((unsigned int)f2bf(a.w) << 16);
    unsigned int p2 = f2bf(b.x) | ((unsigned int)f2bf(b.y) << 16);
    unsigned int p3 = f2bf(b.z) | ((unsigned int)f2bf(b.w) << 16);
    *(uint4*)(D + i) = make_uint4(p0, p1, p2, p3);
}

extern "C" void kernel_launch(void* const* d_in, const int* in_sizes, int n_in,
                              void* d_out, int out_size, void* d_ws, size_t ws_size,
                              hipStream_t stream)
{
    const float* x   = (const float*)d_in[0];
    const float* Wq1 = (const float*)d_in[1];
    const float* Wk1 = (const float*)d_in[2];
    const float* Wq2 = (const float*)d_in[3];
    const float* Wk2 = (const float*)d_in[4];
    const float* Wv  = (const float*)d_in[5];
    const float* W1  = (const float*)d_in[6];
    const float* W2  = (const float*)d_in[7];
    float* out = (float*)d_out;

    const int S = 2048, D = 2048;
    const int MS = 8 * S;                          // 16384
    const long long SS = (long long)S * S;         // 4,194,304
    const long long SD = (long long)S * D;

    // ---- workspace layout (bf16 stored as u16 bits) ----
    u16* xb  = (u16*)d_ws;                         // [MS, D]           67.1 MB
    u16* wb  = xb + (size_t)MS * D;                // 7 x [2048,2048]   58.7 MB
    u16* wq1 = wb + 0 * SS; u16* wk1 = wb + 1 * SS;
    u16* wq2 = wb + 2 * SS; u16* wk2 = wb + 3 * SS;
    u16* wv  = wb + 4 * SS; u16* w1  = wb + 5 * SS; u16* w2 = wb + 6 * SS;
    u16* Qb  = wb + 7 * SS;                        // [MS, D]           67.1 MB
    u16* Kb  = Qb + (size_t)MS * D;                // [MS, D]           67.1 MB
    float* Ab = (float*)(Kb + (size_t)MS * D);     // fp32 logits      134.2 MB
    float* S1 = Ab + (size_t)MS * D;               // fp32 score1      134.2 MB
    // aliases (sequentially safe):
    u16* Pb = Qb;          // bf16 probs overwrite Q after QK^T consumed it
    u16* Cb = (u16*)Ab;    // bf16 circle overwrites logits
    u16* Vt = Kb;          // bf16 v^T overwrites K

    const float scale = 1.0f / sqrtf((float)S);

    dim3 blk(256);
    dim3 gFull(D / BN, MS / BM, 1);   // (16,128): shared-weight GEMMs (M=16384)
    dim3 gHead(S / BN, S / BM, 8);    // (16,16,8): per-head batched GEMMs
    dim3 gSm(MS);

    // ---- casts ----
    cast_bf16<<<dim3((MS * (long long)D) / 2048), blk, 0, stream>>>(x, xb);
    cast_bf16<<<dim3(SS / 2048), blk, 0, stream>>>(Wq1, wq1);
    cast_bf16<<<dim3(SS / 2048), blk, 0, stream>>>(Wk1, wk1);
    cast_bf16<<<dim3(SS / 2048), blk, 0, stream>>>(Wq2, wq2);
    cast_bf16<<<dim3(SS / 2048), blk, 0, stream>>>(Wk2, wk2);
    cast_bf16<<<dim3(SS / 2048), blk, 0, stream>>>(Wv, wv);
    cast_bf16<<<dim3(SS / 2048), blk, 0, stream>>>(W1, w1);
    cast_bf16<<<dim3(SS / 2048), blk, 0, stream>>>(W2, w2);

    // ---- pass 1 ----
    gemm_mfma<1,0><<<gFull, blk, 0, stream>>>(xb, wq1, Qb, nullptr, D, D, 0, 0, 0, 0);
    gemm_mfma<1,0><<<gFull, blk, 0, stream>>>(xb, wk1, Kb, nullptr, D, D, 0, 0, 0, 0);
    gemm_mfma<0,0><<<gHead, blk, 0, stream>>>(Qb, Kb, Ab, nullptr, S, D, SS, SS, SS, 0);
    softmax_bf16<<<gSm, blk, 0, stream>>>(Ab, Pb, scale);
    gemm_mfma<0,0><<<gFull, blk, 0, stream>>>(Pb, w1, S1, nullptr, S, S, 0, 0, 0, 0);

    // ---- pass 2 ----
    gemm_mfma<1,0><<<gFull, blk, 0, stream>>>(xb, wq2, Qb, nullptr, D, D, 0, 0, 0, 0);
    gemm_mfma<1,0><<<gFull, blk, 0, stream>>>(xb, wk2, Kb, nullptr, D, D, 0, 0, 0, 0);
    gemm_mfma<0,0><<<gHead, blk, 0, stream>>>(Qb, Kb, Ab, nullptr, S, D, SS, SS, SS, 0);
    softmax_bf16<<<gSm, blk, 0, stream>>>(Ab, Pb, scale);
    // circle = (score1 - P2@W2^T)^2, bf16 out
    gemm_mfma<1,1><<<gFull, blk, 0, stream>>>(Pb, w2, Cb, S1, S, S, 0, 0, 0, 0);

    // ---- v^T and final ----
    // Vt[h,d,t] = sum_e Wv[d,e] x[h,t,e]
    gemm_mfma<1,0><<<gHead, blk, 0, stream>>>(wv, xb, Vt, nullptr, S, D, 0, SD, SS, 0);
    // out[h,s,d] = sum_t circle[h,s,t] Vt[h,d,t]
    gemm_mfma<0,0><<<gHead, blk, 0, stream>>>(Cb, Vt, out, nullptr, D, S, SS, SS, SD, 0);
}

// Round 4
// 1840.048 us; speedup vs baseline: 1.2724x; 1.1291x over previous
//
#include <hip/hip_runtime.h>
#include <math.h>

typedef unsigned short u16;
typedef __bf16 bf16x8 __attribute__((ext_vector_type(8)));
typedef float floatx4 __attribute__((ext_vector_type(4)));

__device__ __forceinline__ u16 f2bf(float f) {
    unsigned int u = __float_as_uint(f);
    u += 0x7FFFu + ((u >> 16) & 1u);          // round-to-nearest-even
    return (u16)(u >> 16);
}

__device__ __forceinline__ void async_load16(const void* g, void* l) {
    __builtin_amdgcn_global_load_lds(
        (const __attribute__((address_space(1))) unsigned int*)g,
        (__attribute__((address_space(3))) unsigned int*)l, 16, 0, 0);
}

#define BM 256
#define BN 256
#define BK 64                      // 8 k-chunks of 8 bf16 (16 B) per row
#define TILE (BM * BK)             // u16 elements per operand tile

// raw barrier (no vmcnt(0) drain like __syncthreads)
#define BAR()        __builtin_amdgcn_s_barrier()
#define WAIT_LGKM0() do { asm volatile("s_waitcnt lgkmcnt(0)" ::: "memory"); \
                          __builtin_amdgcn_sched_barrier(0); } while (0)
#define WAIT_VM(N)   do { asm volatile("s_waitcnt vmcnt(" #N ")" ::: "memory"); \
                          __builtin_amdgcn_sched_barrier(0); } while (0)

// C[M,N] = A[M,K] @ B[N,K]^T, bf16 in (u16 bits), fp32 accumulate.
// 256x256 tile, BK=64, 8 waves (2M x 4N), double-buffered LDS (128 KiB),
// 4 phases/K-tile, counted vmcnt (A staged 1 tile ahead, B 2 tiles ahead).
// Per-wave vmcnt ledger (2 loads per stage call):
//   entering tile t: 4 outstanding (B of t+1)
//   q0 +2 (A t+1 h0), q1 +2 (A t+1 h1), q2 +2 (B t+2 h0), q3 +2 (B t+2 h1) -> 12
//   q3 WAIT_VM(4): retires B(t+1)+A(t+1) (everything tile t+1 reads), keeps
//   B(t+2) in flight across the tile boundary (never drains to 0 mid-loop).
// Numerics: K accumulated in order (two k=32 halves per BK) — identical to the
// verified BK=32 kernel.
// OUT_BF16: store bf16 bits. EPI: C = (E - acc)^2. blockIdx.z batches via strides.
template<int OUT_BF16, int EPI>
__global__ __launch_bounds__(512, 2)
void gemm_mfma(const u16* __restrict__ A, const u16* __restrict__ B,
               void* __restrict__ Cv, const float* __restrict__ E,
               int N, int K,
               long long sA, long long sB, long long sC, long long sE)
{
    __shared__ u16 As[2 * TILE];   // 64 KB: [buf][row 0..255][BK], chunks XOR-swizzled
    __shared__ u16 Bs[2 * TILE];   // 64 KB

    const long long z = blockIdx.z;
    A += z * sA;
    B += z * sB;

    // ---- XCD-aware bijective block swizzle (x-y plane; nwg % 8 == 0 here) ----
    const int gx = gridDim.x;
    const int nwg = gx * gridDim.y;
    int wg = blockIdx.y * gx + blockIdx.x;
    if ((nwg & 7) == 0) wg = (wg & 7) * (nwg >> 3) + (wg >> 3);
    const int bx = wg % gx, by = wg / gx;

    const int tid  = threadIdx.x;
    const int w    = tid >> 6;         // wave 0..7
    const int lane = tid & 63;

    // ---- staging addressing ----
    // One global_load_lds per wave writes 8 rows (8 lanes/row, 16 B each).
    // LDS slot s of row r holds global k-chunk s ^ (r & 7); dest is linear
    // (wave-uniform base + lane*16 B), so the XOR is applied to the per-lane
    // GLOBAL source (m173 pattern). Here r&7 == lane>>3.
    const int srow = (w << 3) + (lane >> 3);                 // 0..63
    const int skc  = (lane & 7) ^ (lane >> 3);               // swizzled src k-chunk
    const u16* Ag = A + ((long long)by * BM + srow) * K + skc * 8;
    const u16* Bg = B + ((long long)bx * BN + srow) * K + skc * 8;
    u16* AsS = As + srow * BK + (lane & 7) * 8;
    u16* BsS = Bs + srow * BK + (lane & 7) * 8;
    const long long rK64  = (long long)64 * K;
    const long long rK128 = (long long)128 * K;

    // stage one 128-row half-tile: 2 loads/thread (rows srow, srow+64)
    auto stageA = [&](int buf, int t, int h) {
        const u16* g = Ag + (long long)h * rK128 + (long long)t * BK;
        u16* l = AsS + buf * TILE + h * (128 * BK);
        async_load16(g, l);
        async_load16(g + rK64, l + 64 * BK);
    };
    auto stageB = [&](int buf, int t, int h) {
        const u16* g = Bg + (long long)h * rK128 + (long long)t * BK;
        u16* l = BsS + buf * TILE + h * (128 * BK);
        async_load16(g, l);
        async_load16(g + rK64, l + 64 * BK);
    };

    // ---- compute-side fragment addressing ----
    const int wrow = w >> 2, wcol = w & 3;          // wave 2x4 -> 128x64 per wave
    const int frow = lane & 15, quad = lane >> 4;
    const int sw0  = ((quad ^ (frow & 7)) << 3);    // u16 slot offset, k-half 0
    const int aoff = (wrow * 128 + frow) * BK;      // + i*16*BK + slot
    const int boff = (wcol * 64  + frow) * BK;      // + j*16*BK + slot

    floatx4 acc[8][4];
#pragma unroll
    for (int i = 0; i < 8; i++)
#pragma unroll
        for (int j = 0; j < 4; j++) acc[i][j] = (floatx4)0.0f;

    const int NT = K / BK;

    // ---- prologue: tile0 full, tile1 B halves (left in flight) ----
    stageA(0, 0, 0); stageA(0, 0, 1);
    stageB(0, 0, 0); stageB(0, 0, 1);
    if (NT > 1) {
        stageB(1, 1, 0); stageB(1, 1, 1);
        WAIT_VM(4);                      // tile0's 8 loads landed; tile1 B in flight
    } else {
        WAIT_VM(0);
    }
    BAR();

    union F { int4 i4; bf16x8 v; };

    for (int t = 0; t < NT; ++t) {
        const int b = t & 1;
        const int abase = b * TILE + aoff;
        const int bbase = b * TILE + boff;
        const bool t1ok = (t + 1 < NT);
        const bool t2ok = (t + 2 < NT);
        F bfr[4][2];

#pragma unroll
        for (int q = 0; q < 4; ++q) {
            // --- ds reads for this phase (B once per tile, A per quadrant) ---
            if (q == 0) {
#pragma unroll
                for (int j = 0; j < 4; ++j) {
                    bfr[j][0].i4 = *(const int4*)&Bs[bbase + j * (16 * BK) + sw0];
                    bfr[j][1].i4 = *(const int4*)&Bs[bbase + j * (16 * BK) + (sw0 ^ 32)];
                }
            }
            F af[2][2];
#pragma unroll
            for (int ii = 0; ii < 2; ++ii) {
                const int ro = abase + (2 * q + ii) * (16 * BK);
                af[ii][0].i4 = *(const int4*)&As[ro + sw0];
                af[ii][1].i4 = *(const int4*)&As[ro + (sw0 ^ 32)];
            }
            // --- stage one half-tile per phase:
            //     A of t+1 (q0,q1; buffer b^1 fully read by end of tile t-1),
            //     B of t+2 (q2,q3; this buffer's B only read in q0, and the
            //     end-of-q0 barrier proved all waves finished those reads) ---
            if (q == 0 && t1ok) stageA(b ^ 1, t + 1, 0);
            if (q == 1 && t1ok) stageA(b ^ 1, t + 1, 1);
            if (q == 2 && t2ok) stageB(b,     t + 2, 0);
            if (q == 3 && t2ok) stageB(b,     t + 2, 1);

            BAR();
            WAIT_LGKM0();
            __builtin_amdgcn_s_setprio(1);
#pragma unroll
            for (int kk = 0; kk < 2; ++kk)
#pragma unroll
                for (int ii = 0; ii < 2; ++ii)
#pragma unroll
                    for (int j = 0; j < 4; ++j)
                        acc[2 * q + ii][j] = __builtin_amdgcn_mfma_f32_16x16x32_bf16(
                            af[ii][kk].v, bfr[j][kk].v, acc[2 * q + ii][j], 0, 0, 0);
            __builtin_amdgcn_s_setprio(0);

            if (q == 3) {
                // counted wait: keep ONLY B of t+2 (4 loads) in flight.
                if (t2ok) { WAIT_VM(4); } else { WAIT_VM(0); }
            }
            BAR();
        }
    }

    // ---- epilogue: C/D layout col=lane&15, row=quad*4+reg ----
    const long long crow0 = (long long)by * BM + wrow * 128 + quad * 4;
    const long long ccol0 = (long long)bx * BN + wcol * 64 + frow;
    u16*   Cb = (u16*)Cv   + z * sC;
    float* Cf = (float*)Cv + z * sC;
    const float* Ep = EPI ? (E + z * sE) : nullptr;
#pragma unroll
    for (int i = 0; i < 8; ++i) {
#pragma unroll
        for (int r = 0; r < 4; ++r) {
            const long long gr = crow0 + 16 * i + r;
            const long long rb = gr * (long long)N;
#pragma unroll
            for (int j = 0; j < 4; ++j) {
                const long long gc = ccol0 + 16 * j;
                float v = acc[i][j][r];
                if (EPI) {
                    const float e = Ep[rb + gc];
                    const float d = e - v;
                    v = d * d;
                }
                if (OUT_BF16) Cb[rb + gc] = f2bf(v);
                else          Cf[rb + gc] = v;
            }
        }
    }
}

// row softmax over 2048 cols: O = bf16(softmax(P * scale)), P fp32
__global__ __launch_bounds__(256)
void softmax_bf16(const float* __restrict__ P, u16* __restrict__ O, float scale)
{
    const long long rb = (long long)blockIdx.x * 2048;
    const float* p = P + rb;
    const int tid = threadIdx.x;

    const float4 x0 = *(const float4*)(p + tid * 8);
    const float4 x1 = *(const float4*)(p + tid * 8 + 4);
    float v[8] = {x0.x, x0.y, x0.z, x0.w, x1.x, x1.y, x1.z, x1.w};

    float m = -1e30f;
#pragma unroll
    for (int j = 0; j < 8; j++) { v[j] *= scale; m = fmaxf(m, v[j]); }
#pragma unroll
    for (int off = 32; off; off >>= 1) m = fmaxf(m, __shfl_xor(m, off));

    __shared__ float smax[4];
    __shared__ float ssum[4];
    const int wid = tid >> 6, lane = tid & 63;
    if (lane == 0) smax[wid] = m;
    __syncthreads();
    m = fmaxf(fmaxf(smax[0], smax[1]), fmaxf(smax[2], smax[3]));

    float s = 0.f;
#pragma unroll
    for (int j = 0; j < 8; j++) { v[j] = __expf(v[j] - m); s += v[j]; }
#pragma unroll
    for (int off = 32; off; off >>= 1) s += __shfl_xor(s, off);
    if (lane == 0) ssum[wid] = s;
    __syncthreads();
    const float inv = 1.f / (ssum[0] + ssum[1] + ssum[2] + ssum[3]);

    unsigned int p0 = f2bf(v[0] * inv) | ((unsigned int)f2bf(v[1] * inv) << 16);
    unsigned int p1 = f2bf(v[2] * inv) | ((unsigned int)f2bf(v[3] * inv) << 16);
    unsigned int p2 = f2bf(v[4] * inv) | ((unsigned int)f2bf(v[5] * inv) << 16);
    unsigned int p3 = f2bf(v[6] * inv) | ((unsigned int)f2bf(v[7] * inv) << 16);
    *(uint4*)(O + rb + tid * 8) = make_uint4(p0, p1, p2, p3);
}

// fp32 -> bf16 bits, 8 elems/thread; n must be a multiple of 2048
__global__ __launch_bounds__(256)
void cast_bf16(const float* __restrict__ S, u16* __restrict__ D)
{
    const long long i = ((long long)blockIdx.x * 256 + threadIdx.x) * 8;
    const float4 a = *(const float4*)(S + i);
    const float4 b = *(const float4*)(S + i + 4);
    unsigned int p0 = f2bf(a.x) | ((unsigned int)f2bf(a.y) << 16);
    unsigned int p1 = f2bf(a.z) | ((unsigned int)f2bf(a.w) << 16);
    unsigned int p2 = f2bf(b.x) | ((unsigned int)f2bf(b.y) << 16);
    unsigned int p3 = f2bf(b.z) | ((unsigned int)f2bf(b.w) << 16);
    *(uint4*)(D + i) = make_uint4(p0, p1, p2, p3);
}

extern "C" void kernel_launch(void* const* d_in, const int* in_sizes, int n_in,
                              void* d_out, int out_size, void* d_ws, size_t ws_size,
                              hipStream_t stream)
{
    const float* x   = (const float*)d_in[0];
    const float* Wq1 = (const float*)d_in[1];
    const float* Wk1 = (const float*)d_in[2];
    const float* Wq2 = (const float*)d_in[3];
    const float* Wk2 = (const float*)d_in[4];
    const float* Wv  = (const float*)d_in[5];
    const float* W1  = (const float*)d_in[6];
    const float* W2  = (const float*)d_in[7];
    float* out = (float*)d_out;

    const int S = 2048, D = 2048;
    const int MS = 8 * S;                          // 16384
    const long long SS = (long long)S * S;         // 4,194,304
    const long long SD = (long long)S * D;

    // ---- workspace layout (bf16 stored as u16 bits) ----
    u16* xb  = (u16*)d_ws;                         // [MS, D]           67.1 MB
    u16* wb  = xb + (size_t)MS * D;                // 7 x [2048,2048]   58.7 MB
    u16* wq1 = wb + 0 * SS; u16* wk1 = wb + 1 * SS;
    u16* wq2 = wb + 2 * SS; u16* wk2 = wb + 3 * SS;
    u16* wv  = wb + 4 * SS; u16* w1  = wb + 5 * SS; u16* w2 = wb + 6 * SS;
    u16* Qb  = wb + 7 * SS;                        // [MS, D]           67.1 MB
    u16* Kb  = Qb + (size_t)MS * D;                // [MS, D]           67.1 MB
    float* Ab = (float*)(Kb + (size_t)MS * D);     // fp32 logits      134.2 MB
    float* S1 = Ab + (size_t)MS * D;               // fp32 score1      134.2 MB
    // aliases (sequentially safe):
    u16* Pb = Qb;          // bf16 probs overwrite Q after QK^T consumed it
    u16* Cb = (u16*)Ab;    // bf16 circle overwrites logits
    u16* Vt = Kb;          // bf16 v^T overwrites K

    const float scale = 1.0f / sqrtf((float)S);

    dim3 blk(256);
    dim3 blkG(512);                    // 8 waves for the 256x256 GEMM
    dim3 gFull(D / BN, MS / BM, 1);    // (8, 64): shared-weight GEMMs (M=16384)
    dim3 gHead(S / BN, S / BM, 8);     // (8, 8, 8): per-head batched GEMMs
    dim3 gSm(MS);

    // ---- casts ----
    cast_bf16<<<dim3((MS * (long long)D) / 2048), blk, 0, stream>>>(x, xb);
    cast_bf16<<<dim3(SS / 2048), blk, 0, stream>>>(Wq1, wq1);
    cast_bf16<<<dim3(SS / 2048), blk, 0, stream>>>(Wk1, wk1);
    cast_bf16<<<dim3(SS / 2048), blk, 0, stream>>>(Wq2, wq2);
    cast_bf16<<<dim3(SS / 2048), blk, 0, stream>>>(Wk2, wk2);
    cast_bf16<<<dim3(SS / 2048), blk, 0, stream>>>(Wv, wv);
    cast_bf16<<<dim3(SS / 2048), blk, 0, stream>>>(W1, w1);
    cast_bf16<<<dim3(SS / 2048), blk, 0, stream>>>(W2, w2);

    // ---- pass 1 ----
    gemm_mfma<1,0><<<gFull, blkG, 0, stream>>>(xb, wq1, Qb, nullptr, D, D, 0, 0, 0, 0);
    gemm_mfma<1,0><<<gFull, blkG, 0, stream>>>(xb, wk1, Kb, nullptr, D, D, 0, 0, 0, 0);
    gemm_mfma<0,0><<<gHead, blkG, 0, stream>>>(Qb, Kb, Ab, nullptr, S, D, SS, SS, SS, 0);
    softmax_bf16<<<gSm, blk, 0, stream>>>(Ab, Pb, scale);
    gemm_mfma<0,0><<<gFull, blkG, 0, stream>>>(Pb, w1, S1, nullptr, S, S, 0, 0, 0, 0);

    // ---- pass 2 ----
    gemm_mfma<1,0><<<gFull, blkG, 0, stream>>>(xb, wq2, Qb, nullptr, D, D, 0, 0, 0, 0);
    gemm_mfma<1,0><<<gFull, blkG, 0, stream>>>(xb, wk2, Kb, nullptr, D, D, 0, 0, 0, 0);
    gemm_mfma<0,0><<<gHead, blkG, 0, stream>>>(Qb, Kb, Ab, nullptr, S, D, SS, SS, SS, 0);
    softmax_bf16<<<gSm, blk, 0, stream>>>(Ab, Pb, scale);
    // circle = (score1 - P2@W2^T)^2, bf16 out
    gemm_mfma<1,1><<<gFull, blkG, 0, stream>>>(Pb, w2, Cb, S1, S, S, 0, 0, 0, 0);

    // ---- v^T and final ----
    // Vt[h,d,t] = sum_e Wv[d,e] x[h,t,e]
    gemm_mfma<1,0><<<gHead, blkG, 0, stream>>>(wv, xb, Vt, nullptr, S, D, 0, SD, SS, 0);
    // out[h,s,d] = sum_t circle[h,s,t] Vt[h,d,t]
    gemm_mfma<0,0><<<gHead, blkG, 0, stream>>>(Cb, Vt, out, nullptr, D, S, SS, SS, SD, 0);
}